// Round 8
// baseline (395.658 us; speedup 1.0000x reference)
//
#include <hip/hip_runtime.h>
#include <hip/hip_bf16.h>
#include <math.h>

// GNNConv rewrites:
//  (1) msg @ f_w = rel @ f_w[0:3] + x[src] @ f_w[3:]  -> per-node Yb (bf16) instead of per-edge GEMM
//  (2) dst-sorted aggregation (ushort src indices), wave-per-dst, zero atomics
//  (3) node_pre fuses delta + Yb (MFMA, no LDS/barriers); gemm_g fuses both g-layers (MFMA)
//  (4) r8: hist fused into node_pre's grid (atomics overlap MFMA); 3 scan kernels -> 1
//      single-block scan; aggregate does 4 edges/iter (quarter-wave, uint4 = 8 bf16/lane).

typedef __attribute__((ext_vector_type(8))) short bf16x8;
typedef __attribute__((ext_vector_type(4))) float f32x4;

#define LEAKY(v) ((v) >= 0.0f ? (v) : 0.01f * (v))

static __device__ __forceinline__ unsigned short f2bf(float f) {
    unsigned u = __float_as_uint(f);
    u = (u + 0x7fffu + ((u >> 16) & 1u)) >> 16;   // RNE
    return (unsigned short)u;
}

union ABu { unsigned short u[8]; bf16x8 v; };

static __device__ __forceinline__ bf16x8 cvt8(const float* __restrict__ p) {
    ABu r;
    const float4 v0 = *(const float4*)p;
    const float4 v1 = *(const float4*)(p + 4);
    r.u[0] = f2bf(v0.x); r.u[1] = f2bf(v0.y); r.u[2] = f2bf(v0.z); r.u[3] = f2bf(v0.w);
    r.u[4] = f2bf(v1.x); r.u[5] = f2bf(v1.y); r.u[6] = f2bf(v1.z); r.u[7] = f2bf(v1.w);
    return r.v;
}

static __device__ __forceinline__ bf16x8 zero_ab() {
    ABu r;
    #pragma unroll
    for (int i = 0; i < 8; ++i) r.u[i] = 0;
    return r.v;
}

// ---------------- weight prep: bf16 transposed copies (W^T[n][k]) ----------------
__global__ __launch_bounds__(128) void prep_weights(
    const float* __restrict__ h_w1, const float* __restrict__ f_w,
    const float* __restrict__ g_w1, const float* __restrict__ g_w2,
    unsigned short* __restrict__ Wht, unsigned short* __restrict__ Wft,
    unsigned short* __restrict__ G1t, unsigned short* __restrict__ G2t)
{
    const int j = blockIdx.x;      // output channel (row of W^T)
    const int k = threadIdx.x;     // k index
    Wht[j * 128 + k] = f2bf(h_w1[(size_t)k * 128 + j]);
    Wft[j * 128 + k] = f2bf(f_w[(size_t)(3 + k) * 128 + j]);
    G1t[j * 128 + k] = f2bf(g_w1[(size_t)k * 128 + j]);
    G2t[j * 128 + k] = f2bf(g_w2[(size_t)k * 128 + j]);
}

// ---------------- node_pre (MFMA) + fused edge histogram ----------------
// blocks [0, tile_blocks): delta = tanh(leaky(x@h_w1+b1)@h_w2+b2); Yb = bf16(x@f_w[3:]+f_b)
// blocks [tile_blocks, ...): histogram of edge dst (atomics overlap the MFMA blocks)
__global__ __launch_bounds__(256) void node_pre_hist(
    const float* __restrict__ x,
    const unsigned short* __restrict__ Wht, const float* __restrict__ h_b1,
    const float* __restrict__ h_w2, const float* __restrict__ h_b2,
    const unsigned short* __restrict__ Wft, const float* __restrict__ f_b,
    float* __restrict__ delta, unsigned short* __restrict__ Yb, int N,
    const int* __restrict__ ei, int* __restrict__ counts, int E, int tile_blocks)
{
    if ((int)blockIdx.x >= tile_blocks) {
        const int e = (blockIdx.x - tile_blocks) * 256 + threadIdx.x;
        if (e < E) atomicAdd(&counts[ei[(size_t)E + e]], 1);
        return;
    }

    const int lane = threadIdx.x & 63;
    const int wave = threadIdx.x >> 6;
    const int quad = lane >> 4;
    const int l16  = lane & 15;
    const int row0 = blockIdx.x * 64 + wave * 16;

    // A-fragments: A[m=l16][k=quad*8+j], 4 k-chunks of 32
    bf16x8 a[4];
    {
        const int row = row0 + l16;
        if (row < N) {
            const float* xp = x + (size_t)row * 128 + quad * 8;
            #pragma unroll
            for (int kc = 0; kc < 4; ++kc) a[kc] = cvt8(xp + kc * 32);
        } else {
            #pragma unroll
            for (int kc = 0; kc < 4; ++kc) a[kc] = zero_ab();
        }
    }

    f32x4 acch[8], accf[8];
    #pragma unroll
    for (int nt = 0; nt < 8; ++nt) {
        acch[nt] = (f32x4){0.f, 0.f, 0.f, 0.f};
        accf[nt] = (f32x4){0.f, 0.f, 0.f, 0.f};
    }

    #pragma unroll
    for (int nt = 0; nt < 8; ++nt) {
        const unsigned short* wh = Wht + (size_t)(nt * 16 + l16) * 128 + quad * 8;
        const unsigned short* wf = Wft + (size_t)(nt * 16 + l16) * 128 + quad * 8;
        #pragma unroll
        for (int kc = 0; kc < 4; ++kc) {
            const bf16x8 bh = *(const bf16x8*)(wh + kc * 32);
            const bf16x8 bf_ = *(const bf16x8*)(wf + kc * 32);
            acch[nt] = __builtin_amdgcn_mfma_f32_16x16x32_bf16(a[kc], bh, acch[nt], 0, 0, 0);
            accf[nt] = __builtin_amdgcn_mfma_f32_16x16x32_bf16(a[kc], bf_, accf[nt], 0, 0, 0);
        }
    }

    // Epilogue. C/D layout: col = nt*16 + l16, local row = quad*4 + reg.
    float p[4][3];
    #pragma unroll
    for (int r = 0; r < 4; ++r) { p[r][0] = 0.f; p[r][1] = 0.f; p[r][2] = 0.f; }

    #pragma unroll
    for (int nt = 0; nt < 8; ++nt) {
        const int col = nt * 16 + l16;
        const float b1 = h_b1[col];
        const float fb = f_b[col];
        const float w20 = h_w2[col * 3 + 0];
        const float w21 = h_w2[col * 3 + 1];
        const float w22 = h_w2[col * 3 + 2];
        #pragma unroll
        for (int reg = 0; reg < 4; ++reg) {
            const int grow = row0 + quad * 4 + reg;
            float h = acch[nt][reg] + b1;
            h = LEAKY(h);
            p[reg][0] += h * w20;
            p[reg][1] += h * w21;
            p[reg][2] += h * w22;
            if (grow < N)
                Yb[(size_t)grow * 128 + col] = f2bf(accf[nt][reg] + fb);
        }
    }

    // reduce p across the 16 l16 lanes (within quad)
    #pragma unroll
    for (int reg = 0; reg < 4; ++reg)
        #pragma unroll
        for (int c = 0; c < 3; ++c) {
            float v = p[reg][c];
            v += __shfl_down(v, 8);
            v += __shfl_down(v, 4);
            v += __shfl_down(v, 2);
            v += __shfl_down(v, 1);
            p[reg][c] = v;
        }

    if (l16 == 0) {
        #pragma unroll
        for (int reg = 0; reg < 4; ++reg) {
            const int grow = row0 + quad * 4 + reg;
            if (grow < N) {
                delta[(size_t)grow * 3 + 0] = tanhf(p[reg][0] + h_b2[0]);
                delta[(size_t)grow * 3 + 1] = tanhf(p[reg][1] + h_b2[1]);
                delta[(size_t)grow * 3 + 2] = tanhf(p[reg][2] + h_b2[2]);
            }
        }
    }
}

// ---------------- single-block exclusive scan over counts[N] -> offs[N] ----------------
__global__ __launch_bounds__(1024) void scan_all(
    const int* __restrict__ counts, int* __restrict__ offs, int N)
{
    __shared__ int s[1024];
    const int tid = threadIdx.x;
    const int per = (N + 1023) / 1024;
    const int base = tid * per;

    int sum = 0;
    for (int i = 0; i < per; ++i) {
        const int idx = base + i;
        if (idx < N) sum += counts[idx];
    }
    s[tid] = sum;
    __syncthreads();
    for (int d = 1; d < 1024; d <<= 1) {
        int t = (tid >= d) ? s[tid - d] : 0;
        __syncthreads();
        s[tid] += t;
        __syncthreads();
    }
    int run = s[tid] - sum;   // exclusive prefix of this thread's chunk
    for (int i = 0; i < per; ++i) {
        const int idx = base + i;
        if (idx < N) {
            const int c = counts[idx];
            offs[idx] = run;
            run += c;
        }
    }
}

// ---------------- scatter src indices into dst-sorted order ----------------
__global__ __launch_bounds__(256) void scatter_kernel(
    const int* __restrict__ ei, int* __restrict__ offs,
    unsigned short* __restrict__ srcs_sorted, int E)
{
    const int e = blockIdx.x * 256 + threadIdx.x;
    if (e < E) {
        const int src = ei[e];
        const int dst = ei[(size_t)E + e];
        const int p = atomicAdd(&offs[dst], 1);
        srcs_sorted[p] = (unsigned short)src;   // N < 65536
    }
}

// ---------------- aggregation: wave-per-dst, 4 edges/iter (quarter-wave each) ----------------
// lane L: quarter = L>>4, channels cl = (L&15)*8. One uint4 (8 bf16) gather per lane per iter.
// Final __shfl_xor(16)+__shfl_xor(32) combine; quarter 0 stores two float4s (coalesced row).
__global__ __launch_bounds__(256) void aggregate_kernel(
    const unsigned short* __restrict__ srcs_sorted,
    const int* __restrict__ offs_end,      // start + count
    const int* __restrict__ counts,
    const float* __restrict__ pos,         // [N,3]
    const float* __restrict__ delta,       // [N,3]
    const unsigned short* __restrict__ Yb, // [N,128] bf16
    const float* __restrict__ fw3,         // [3][128]
    float* __restrict__ aggr,              // [N,128] = d_out
    int N)
{
    const int lane = threadIdx.x & 63;
    const int d = blockIdx.x * 4 + (threadIdx.x >> 6);
    if (d >= N) return;

    const int quarter = lane >> 4;
    const int cl      = (lane & 15) * 8;

    float wx[8], wy[8], wz[8];
    #pragma unroll
    for (int j = 0; j < 8; ++j) {
        wx[j] = fw3[cl + j];
        wy[j] = fw3[128 + cl + j];
        wz[j] = fw3[256 + cl + j];
    }

    const int len   = counts[d];
    const int start = offs_end[d] - len;
    const float q0 = delta[(size_t)d * 3 + 0] - pos[(size_t)d * 3 + 0];
    const float q1 = delta[(size_t)d * 3 + 1] - pos[(size_t)d * 3 + 1];
    const float q2 = delta[(size_t)d * 3 + 2] - pos[(size_t)d * 3 + 2];

    float acc[8] = {0.f, 0.f, 0.f, 0.f, 0.f, 0.f, 0.f, 0.f};

    for (int chunk = 0; chunk < len; chunk += 64) {
        const int m = min(64, len - chunk);
        int idx = 0; float rx = 0.f, ry = 0.f, rz = 0.f;
        if (lane < m) {
            idx = srcs_sorted[start + chunk + lane];
            rx = pos[(size_t)idx * 3 + 0] + q0;
            ry = pos[(size_t)idx * 3 + 1] + q1;
            rz = pos[(size_t)idx * 3 + 2] + q2;
        }
        int t = 0;
        #pragma unroll 2
        for (; t + 4 <= m; t += 4) {
            const int e = t + quarter;
            const int   s  = __shfl(idx, e);
            const float r0 = __shfl(rx, e);
            const float r1 = __shfl(ry, e);
            const float r2 = __shfl(rz, e);
            const uint4 y = *(const uint4*)(Yb + (size_t)s * 128 + cl);
            const float f0 = __uint_as_float((y.x & 0xffffu) << 16);
            const float f1 = __uint_as_float(y.x & 0xffff0000u);
            const float f2 = __uint_as_float((y.y & 0xffffu) << 16);
            const float f3 = __uint_as_float(y.y & 0xffff0000u);
            const float f4 = __uint_as_float((y.z & 0xffffu) << 16);
            const float f5 = __uint_as_float(y.z & 0xffff0000u);
            const float f6 = __uint_as_float((y.w & 0xffffu) << 16);
            const float f7 = __uint_as_float(y.w & 0xffff0000u);
            float z0 = f0 + r0 * wx[0] + r1 * wy[0] + r2 * wz[0];
            float z1 = f1 + r0 * wx[1] + r1 * wy[1] + r2 * wz[1];
            float z2 = f2 + r0 * wx[2] + r1 * wy[2] + r2 * wz[2];
            float z3 = f3 + r0 * wx[3] + r1 * wy[3] + r2 * wz[3];
            float z4 = f4 + r0 * wx[4] + r1 * wy[4] + r2 * wz[4];
            float z5 = f5 + r0 * wx[5] + r1 * wy[5] + r2 * wz[5];
            float z6 = f6 + r0 * wx[6] + r1 * wy[6] + r2 * wz[6];
            float z7 = f7 + r0 * wx[7] + r1 * wy[7] + r2 * wz[7];
            acc[0] += LEAKY(z0); acc[1] += LEAKY(z1);
            acc[2] += LEAKY(z2); acc[3] += LEAKY(z3);
            acc[4] += LEAKY(z4); acc[5] += LEAKY(z5);
            acc[6] += LEAKY(z6); acc[7] += LEAKY(z7);
        }
        if (t < m) {   // tail: up to 3 edges, predicated per-quarter
            const int e = t + quarter;       // <= 63 always
            const int   s  = __shfl(idx, e);
            const float r0 = __shfl(rx, e);
            const float r1 = __shfl(ry, e);
            const float r2 = __shfl(rz, e);
            if (e < m) {
                const uint4 y = *(const uint4*)(Yb + (size_t)s * 128 + cl);
                const float f0 = __uint_as_float((y.x & 0xffffu) << 16);
                const float f1 = __uint_as_float(y.x & 0xffff0000u);
                const float f2 = __uint_as_float((y.y & 0xffffu) << 16);
                const float f3 = __uint_as_float(y.y & 0xffff0000u);
                const float f4 = __uint_as_float((y.z & 0xffffu) << 16);
                const float f5 = __uint_as_float(y.z & 0xffff0000u);
                const float f6 = __uint_as_float((y.w & 0xffffu) << 16);
                const float f7 = __uint_as_float(y.w & 0xffff0000u);
                float z0 = f0 + r0 * wx[0] + r1 * wy[0] + r2 * wz[0];
                float z1 = f1 + r0 * wx[1] + r1 * wy[1] + r2 * wz[1];
                float z2 = f2 + r0 * wx[2] + r1 * wy[2] + r2 * wz[2];
                float z3 = f3 + r0 * wx[3] + r1 * wy[3] + r2 * wz[3];
                float z4 = f4 + r0 * wx[4] + r1 * wy[4] + r2 * wz[4];
                float z5 = f5 + r0 * wx[5] + r1 * wy[5] + r2 * wz[5];
                float z6 = f6 + r0 * wx[6] + r1 * wy[6] + r2 * wz[6];
                float z7 = f7 + r0 * wx[7] + r1 * wy[7] + r2 * wz[7];
                acc[0] += LEAKY(z0); acc[1] += LEAKY(z1);
                acc[2] += LEAKY(z2); acc[3] += LEAKY(z3);
                acc[4] += LEAKY(z4); acc[5] += LEAKY(z5);
                acc[6] += LEAKY(z6); acc[7] += LEAKY(z7);
            }
        }
    }

    #pragma unroll
    for (int j = 0; j < 8; ++j) {
        acc[j] += __shfl_xor(acc[j], 16);
        acc[j] += __shfl_xor(acc[j], 32);
    }
    if (quarter == 0) {
        *(float4*)(aggr + (size_t)d * 128 + cl) =
            make_float4(acc[0], acc[1], acc[2], acc[3]);
        *(float4*)(aggr + (size_t)d * 128 + cl + 4) =
            make_float4(acc[4], acc[5], acc[6], acc[7]);
    }
}

// ---------------- gemm_g (MFMA): out = leaky(aggr@g_w1+b1)@g_w2 + b2 + x (in-place aggr==out) ----
__global__ __launch_bounds__(256) void gemm_g(
    const float* __restrict__ aggr,
    const unsigned short* __restrict__ G1t, const float* __restrict__ g_b1,
    const unsigned short* __restrict__ G2t, const float* __restrict__ g_b2,
    const float* __restrict__ x,
    float* __restrict__ out, int N)
{
    __shared__ unsigned short Ts[64][136];   // +8 pad -> 2-way bank access on b128 reads

    const int lane = threadIdx.x & 63;
    const int wave = threadIdx.x >> 6;
    const int quad = lane >> 4;
    const int l16  = lane & 15;
    const int row0 = blockIdx.x * 64 + wave * 16;

    // phase 1: A from fp32 aggr
    bf16x8 a[4];
    {
        const int row = row0 + l16;
        if (row < N) {
            const float* ap = aggr + (size_t)row * 128 + quad * 8;
            #pragma unroll
            for (int kc = 0; kc < 4; ++kc) a[kc] = cvt8(ap + kc * 32);
        } else {
            #pragma unroll
            for (int kc = 0; kc < 4; ++kc) a[kc] = zero_ab();
        }
    }

    f32x4 acc[8];
    #pragma unroll
    for (int nt = 0; nt < 8; ++nt) acc[nt] = (f32x4){0.f, 0.f, 0.f, 0.f};

    #pragma unroll
    for (int nt = 0; nt < 8; ++nt) {
        const unsigned short* wp = G1t + (size_t)(nt * 16 + l16) * 128 + quad * 8;
        #pragma unroll
        for (int kc = 0; kc < 4; ++kc) {
            const bf16x8 b = *(const bf16x8*)(wp + kc * 32);
            acc[nt] = __builtin_amdgcn_mfma_f32_16x16x32_bf16(a[kc], b, acc[nt], 0, 0, 0);
        }
    }

    // T = leaky(acc + b1) -> bf16 LDS (C layout: col=nt*16+l16, row=wave*16+quad*4+reg)
    #pragma unroll
    for (int nt = 0; nt < 8; ++nt) {
        const int col = nt * 16 + l16;
        const float b1 = g_b1[col];
        #pragma unroll
        for (int reg = 0; reg < 4; ++reg) {
            float t = acc[nt][reg] + b1;
            t = LEAKY(t);
            Ts[wave * 16 + quad * 4 + reg][col] = f2bf(t);
        }
    }
    __syncthreads();

    // phase 2: A from LDS, B = G2t
    bf16x8 a2[4];
    {
        const unsigned short* tp = &Ts[wave * 16 + l16][quad * 8];
        #pragma unroll
        for (int kc = 0; kc < 4; ++kc) a2[kc] = *(const bf16x8*)(tp + kc * 32);
    }

    f32x4 acc2[8];
    #pragma unroll
    for (int nt = 0; nt < 8; ++nt) acc2[nt] = (f32x4){0.f, 0.f, 0.f, 0.f};

    #pragma unroll
    for (int nt = 0; nt < 8; ++nt) {
        const unsigned short* wp = G2t + (size_t)(nt * 16 + l16) * 128 + quad * 8;
        #pragma unroll
        for (int kc = 0; kc < 4; ++kc) {
            const bf16x8 b = *(const bf16x8*)(wp + kc * 32);
            acc2[nt] = __builtin_amdgcn_mfma_f32_16x16x32_bf16(a2[kc], b, acc2[nt], 0, 0, 0);
        }
    }

    // epilogue: + b2 + x
    #pragma unroll
    for (int nt = 0; nt < 8; ++nt) {
        const int col = nt * 16 + l16;
        const float b2 = g_b2[col];
        #pragma unroll
        for (int reg = 0; reg < 4; ++reg) {
            const int grow = row0 + quad * 4 + reg;
            if (grow < N)
                out[(size_t)grow * 128 + col] =
                    acc2[nt][reg] + b2 + x[(size_t)grow * 128 + col];
        }
    }
}

// ---------------- launch ----------------
extern "C" void kernel_launch(void* const* d_in, const int* in_sizes, int n_in,
                              void* d_out, int out_size, void* d_ws, size_t ws_size,
                              hipStream_t stream) {
    const float* x    = (const float*)d_in[0];
    const float* pos  = (const float*)d_in[1];
    const int*   ei   = (const int*)d_in[2];
    const float* h_w1 = (const float*)d_in[3];
    const float* h_b1 = (const float*)d_in[4];
    const float* h_w2 = (const float*)d_in[5];
    const float* h_b2 = (const float*)d_in[6];
    const float* f_w  = (const float*)d_in[7];   // [131,128]
    const float* f_b  = (const float*)d_in[8];
    const float* g_w1 = (const float*)d_in[9];
    const float* g_b1 = (const float*)d_in[10];
    const float* g_w2 = (const float*)d_in[11];
    const float* g_b2 = (const float*)d_in[12];
    float* out = (float*)d_out;

    const int N = in_sizes[0] / 128;
    const int E = in_sizes[2] / 2;

    // ws (~14.8 MB): delta[N*3]f32 | Yb[N*128]u16 | counts[N] | offs[N] | srcs[E]u16 |
    //                Wht/Wft/G1t/G2t [128*128]u16 each
    float* delta          = (float*)d_ws;
    unsigned short* Yb    = (unsigned short*)(delta + (size_t)N * 3);
    int* counts           = (int*)(Yb + (size_t)N * 128);
    int* offs             = counts + N;
    unsigned short* srcs  = (unsigned short*)(offs + N);
    unsigned short* Wht   = srcs + (size_t)E;
    unsigned short* Wft   = Wht + 128 * 128;
    unsigned short* G1t   = Wft + 128 * 128;
    unsigned short* G2t   = G1t + 128 * 128;
    float* aggr           = out;

    const int tile_blocks = (N + 63) / 64;
    const int hist_blocks = (E + 255) / 256;

    hipMemsetAsync(counts, 0, (size_t)N * sizeof(int), stream);

    prep_weights<<<128, 128, 0, stream>>>(h_w1, f_w, g_w1, g_w2, Wht, Wft, G1t, G2t);

    node_pre_hist<<<tile_blocks + hist_blocks, 256, 0, stream>>>(
        x, Wht, h_b1, h_w2, h_b2, Wft, f_b, delta, Yb, N,
        ei, counts, E, tile_blocks);

    scan_all<<<1, 1024, 0, stream>>>(counts, offs, N);

    scatter_kernel<<<hist_blocks, 256, 0, stream>>>(ei, offs, srcs, E);

    aggregate_kernel<<<(N + 3) / 4, 256, 0, stream>>>(
        srcs, offs, counts, pos, delta, Yb, f_w, aggr, N);

    gemm_g<<<tile_blocks, 256, 0, stream>>>(aggr, G1t, g_b1, G2t, g_b2, x, out, N);
}

// Round 9
// 312.366 us; speedup vs baseline: 1.2666x; 1.2666x over previous
//
#include <hip/hip_runtime.h>
#include <hip/hip_bf16.h>
#include <math.h>

// GNNConv rewrites:
//  (1) msg @ f_w = rel @ f_w[0:3] + x[src] @ f_w[3:]  -> per-node Yb (bf16) instead of per-edge GEMM
//  (2) dst-sorted aggregation (ushort src indices), wave-per-dst, zero atomics
//  (3) node_pre fuses delta + Yb (MFMA, no LDS/barriers) + edge histogram in same grid
//  (4) aggregate: 4 edges/iter (quarter-wave, uint4 = 8 bf16/lane)
//  (5) r9: scan back to hierarchical 3-kernel form (r8's single-block scan_all was 95 us
//      at 0.16% occupancy -- one CU serially touching 100k ints; parallel trio is ~15 us)

typedef __attribute__((ext_vector_type(8))) short bf16x8;
typedef __attribute__((ext_vector_type(4))) float f32x4;

#define LEAKY(v) ((v) >= 0.0f ? (v) : 0.01f * (v))

static __device__ __forceinline__ unsigned short f2bf(float f) {
    unsigned u = __float_as_uint(f);
    u = (u + 0x7fffu + ((u >> 16) & 1u)) >> 16;   // RNE
    return (unsigned short)u;
}

union ABu { unsigned short u[8]; bf16x8 v; };

static __device__ __forceinline__ bf16x8 cvt8(const float* __restrict__ p) {
    ABu r;
    const float4 v0 = *(const float4*)p;
    const float4 v1 = *(const float4*)(p + 4);
    r.u[0] = f2bf(v0.x); r.u[1] = f2bf(v0.y); r.u[2] = f2bf(v0.z); r.u[3] = f2bf(v0.w);
    r.u[4] = f2bf(v1.x); r.u[5] = f2bf(v1.y); r.u[6] = f2bf(v1.z); r.u[7] = f2bf(v1.w);
    return r.v;
}

static __device__ __forceinline__ bf16x8 zero_ab() {
    ABu r;
    #pragma unroll
    for (int i = 0; i < 8; ++i) r.u[i] = 0;
    return r.v;
}

// ---------------- weight prep: bf16 transposed copies (W^T[n][k]) ----------------
__global__ __launch_bounds__(128) void prep_weights(
    const float* __restrict__ h_w1, const float* __restrict__ f_w,
    const float* __restrict__ g_w1, const float* __restrict__ g_w2,
    unsigned short* __restrict__ Wht, unsigned short* __restrict__ Wft,
    unsigned short* __restrict__ G1t, unsigned short* __restrict__ G2t)
{
    const int j = blockIdx.x;      // output channel (row of W^T)
    const int k = threadIdx.x;     // k index
    Wht[j * 128 + k] = f2bf(h_w1[(size_t)k * 128 + j]);
    Wft[j * 128 + k] = f2bf(f_w[(size_t)(3 + k) * 128 + j]);
    G1t[j * 128 + k] = f2bf(g_w1[(size_t)k * 128 + j]);
    G2t[j * 128 + k] = f2bf(g_w2[(size_t)k * 128 + j]);
}

// ---------------- node_pre (MFMA) + fused edge histogram ----------------
__global__ __launch_bounds__(256) void node_pre_hist(
    const float* __restrict__ x,
    const unsigned short* __restrict__ Wht, const float* __restrict__ h_b1,
    const float* __restrict__ h_w2, const float* __restrict__ h_b2,
    const unsigned short* __restrict__ Wft, const float* __restrict__ f_b,
    float* __restrict__ delta, unsigned short* __restrict__ Yb, int N,
    const int* __restrict__ ei, int* __restrict__ counts, int E, int tile_blocks)
{
    if ((int)blockIdx.x >= tile_blocks) {
        const int e = (blockIdx.x - tile_blocks) * 256 + threadIdx.x;
        if (e < E) atomicAdd(&counts[ei[(size_t)E + e]], 1);
        return;
    }

    const int lane = threadIdx.x & 63;
    const int wave = threadIdx.x >> 6;
    const int quad = lane >> 4;
    const int l16  = lane & 15;
    const int row0 = blockIdx.x * 64 + wave * 16;

    // A-fragments: A[m=l16][k=quad*8+j], 4 k-chunks of 32
    bf16x8 a[4];
    {
        const int row = row0 + l16;
        if (row < N) {
            const float* xp = x + (size_t)row * 128 + quad * 8;
            #pragma unroll
            for (int kc = 0; kc < 4; ++kc) a[kc] = cvt8(xp + kc * 32);
        } else {
            #pragma unroll
            for (int kc = 0; kc < 4; ++kc) a[kc] = zero_ab();
        }
    }

    f32x4 acch[8], accf[8];
    #pragma unroll
    for (int nt = 0; nt < 8; ++nt) {
        acch[nt] = (f32x4){0.f, 0.f, 0.f, 0.f};
        accf[nt] = (f32x4){0.f, 0.f, 0.f, 0.f};
    }

    #pragma unroll
    for (int nt = 0; nt < 8; ++nt) {
        const unsigned short* wh = Wht + (size_t)(nt * 16 + l16) * 128 + quad * 8;
        const unsigned short* wf = Wft + (size_t)(nt * 16 + l16) * 128 + quad * 8;
        #pragma unroll
        for (int kc = 0; kc < 4; ++kc) {
            const bf16x8 bh = *(const bf16x8*)(wh + kc * 32);
            const bf16x8 bf_ = *(const bf16x8*)(wf + kc * 32);
            acch[nt] = __builtin_amdgcn_mfma_f32_16x16x32_bf16(a[kc], bh, acch[nt], 0, 0, 0);
            accf[nt] = __builtin_amdgcn_mfma_f32_16x16x32_bf16(a[kc], bf_, accf[nt], 0, 0, 0);
        }
    }

    // Epilogue. C/D layout: col = nt*16 + l16, local row = quad*4 + reg.
    float p[4][3];
    #pragma unroll
    for (int r = 0; r < 4; ++r) { p[r][0] = 0.f; p[r][1] = 0.f; p[r][2] = 0.f; }

    #pragma unroll
    for (int nt = 0; nt < 8; ++nt) {
        const int col = nt * 16 + l16;
        const float b1 = h_b1[col];
        const float fb = f_b[col];
        const float w20 = h_w2[col * 3 + 0];
        const float w21 = h_w2[col * 3 + 1];
        const float w22 = h_w2[col * 3 + 2];
        #pragma unroll
        for (int reg = 0; reg < 4; ++reg) {
            const int grow = row0 + quad * 4 + reg;
            float h = acch[nt][reg] + b1;
            h = LEAKY(h);
            p[reg][0] += h * w20;
            p[reg][1] += h * w21;
            p[reg][2] += h * w22;
            if (grow < N)
                Yb[(size_t)grow * 128 + col] = f2bf(accf[nt][reg] + fb);
        }
    }

    // reduce p across the 16 l16 lanes (within quad)
    #pragma unroll
    for (int reg = 0; reg < 4; ++reg)
        #pragma unroll
        for (int c = 0; c < 3; ++c) {
            float v = p[reg][c];
            v += __shfl_down(v, 8);
            v += __shfl_down(v, 4);
            v += __shfl_down(v, 2);
            v += __shfl_down(v, 1);
            p[reg][c] = v;
        }

    if (l16 == 0) {
        #pragma unroll
        for (int reg = 0; reg < 4; ++reg) {
            const int grow = row0 + quad * 4 + reg;
            if (grow < N) {
                delta[(size_t)grow * 3 + 0] = tanhf(p[reg][0] + h_b2[0]);
                delta[(size_t)grow * 3 + 1] = tanhf(p[reg][1] + h_b2[1]);
                delta[(size_t)grow * 3 + 2] = tanhf(p[reg][2] + h_b2[2]);
            }
        }
    }
}

// ---------------- hierarchical scan (counts -> offs), 1024 elems/block ----------------
__global__ __launch_bounds__(256) void scan_local(
    const int* __restrict__ counts, int* __restrict__ offs,
    int* __restrict__ blocksums, int N)
{
    __shared__ int s[256];
    const int tid  = threadIdx.x;
    const int base = blockIdx.x * 1024 + tid * 4;
    int v[4], sum = 0;
    #pragma unroll
    for (int j = 0; j < 4; ++j) {
        v[j] = (base + j < N) ? counts[base + j] : 0;
        sum += v[j];
    }
    s[tid] = sum;
    __syncthreads();
    for (int d = 1; d < 256; d <<= 1) {
        int t = (tid >= d) ? s[tid - d] : 0;
        __syncthreads();
        s[tid] += t;
        __syncthreads();
    }
    int run = s[tid] - sum;
    #pragma unroll
    for (int j = 0; j < 4; ++j) {
        if (base + j < N) offs[base + j] = run;
        run += v[j];
    }
    if (tid == 255) blocksums[blockIdx.x] = s[255];
}

__global__ __launch_bounds__(256) void scan_top(
    int* __restrict__ blocksums, int B)
{
    __shared__ int s[256];
    const int tid = threadIdx.x;
    int v[4], sum = 0;
    const int base = tid * 4;
    #pragma unroll
    for (int j = 0; j < 4; ++j) {
        v[j] = (base + j < B) ? blocksums[base + j] : 0;
        sum += v[j];
    }
    s[tid] = sum;
    __syncthreads();
    for (int d = 1; d < 256; d <<= 1) {
        int t = (tid >= d) ? s[tid - d] : 0;
        __syncthreads();
        s[tid] += t;
        __syncthreads();
    }
    int run = s[tid] - sum;
    #pragma unroll
    for (int j = 0; j < 4; ++j) {
        if (base + j < B) blocksums[base + j] = run;
        run += v[j];
    }
}

__global__ __launch_bounds__(256) void scan_fixup(
    int* __restrict__ offs, const int* __restrict__ blocksums, int N)
{
    const int i = blockIdx.x * 1024 + threadIdx.x * 4;
    const int add = blocksums[blockIdx.x];
    #pragma unroll
    for (int j = 0; j < 4; ++j)
        if (i + j < N) offs[i + j] += add;
}

// ---------------- scatter src indices into dst-sorted order ----------------
__global__ __launch_bounds__(256) void scatter_kernel(
    const int* __restrict__ ei, int* __restrict__ offs,
    unsigned short* __restrict__ srcs_sorted, int E)
{
    const int e = blockIdx.x * 256 + threadIdx.x;
    if (e < E) {
        const int src = ei[e];
        const int dst = ei[(size_t)E + e];
        const int p = atomicAdd(&offs[dst], 1);
        srcs_sorted[p] = (unsigned short)src;   // N < 65536
    }
}

// ---------------- aggregation: wave-per-dst, 4 edges/iter (quarter-wave each) ----------------
__global__ __launch_bounds__(256) void aggregate_kernel(
    const unsigned short* __restrict__ srcs_sorted,
    const int* __restrict__ offs_end,      // start + count
    const int* __restrict__ counts,
    const float* __restrict__ pos,         // [N,3]
    const float* __restrict__ delta,       // [N,3]
    const unsigned short* __restrict__ Yb, // [N,128] bf16
    const float* __restrict__ fw3,         // [3][128]
    float* __restrict__ aggr,              // [N,128] = d_out
    int N)
{
    const int lane = threadIdx.x & 63;
    const int d = blockIdx.x * 4 + (threadIdx.x >> 6);
    if (d >= N) return;

    const int quarter = lane >> 4;
    const int cl      = (lane & 15) * 8;

    float wx[8], wy[8], wz[8];
    #pragma unroll
    for (int j = 0; j < 8; ++j) {
        wx[j] = fw3[cl + j];
        wy[j] = fw3[128 + cl + j];
        wz[j] = fw3[256 + cl + j];
    }

    const int len   = counts[d];
    const int start = offs_end[d] - len;
    const float q0 = delta[(size_t)d * 3 + 0] - pos[(size_t)d * 3 + 0];
    const float q1 = delta[(size_t)d * 3 + 1] - pos[(size_t)d * 3 + 1];
    const float q2 = delta[(size_t)d * 3 + 2] - pos[(size_t)d * 3 + 2];

    float acc[8] = {0.f, 0.f, 0.f, 0.f, 0.f, 0.f, 0.f, 0.f};

    for (int chunk = 0; chunk < len; chunk += 64) {
        const int m = min(64, len - chunk);
        int idx = 0; float rx = 0.f, ry = 0.f, rz = 0.f;
        if (lane < m) {
            idx = srcs_sorted[start + chunk + lane];
            rx = pos[(size_t)idx * 3 + 0] + q0;
            ry = pos[(size_t)idx * 3 + 1] + q1;
            rz = pos[(size_t)idx * 3 + 2] + q2;
        }
        int t = 0;
        #pragma unroll 2
        for (; t + 4 <= m; t += 4) {
            const int e = t + quarter;
            const int   s  = __shfl(idx, e);
            const float r0 = __shfl(rx, e);
            const float r1 = __shfl(ry, e);
            const float r2 = __shfl(rz, e);
            const uint4 y = *(const uint4*)(Yb + (size_t)s * 128 + cl);
            const float f0 = __uint_as_float((y.x & 0xffffu) << 16);
            const float f1 = __uint_as_float(y.x & 0xffff0000u);
            const float f2 = __uint_as_float((y.y & 0xffffu) << 16);
            const float f3 = __uint_as_float(y.y & 0xffff0000u);
            const float f4 = __uint_as_float((y.z & 0xffffu) << 16);
            const float f5 = __uint_as_float(y.z & 0xffff0000u);
            const float f6 = __uint_as_float((y.w & 0xffffu) << 16);
            const float f7 = __uint_as_float(y.w & 0xffff0000u);
            float z0 = f0 + r0 * wx[0] + r1 * wy[0] + r2 * wz[0];
            float z1 = f1 + r0 * wx[1] + r1 * wy[1] + r2 * wz[1];
            float z2 = f2 + r0 * wx[2] + r1 * wy[2] + r2 * wz[2];
            float z3 = f3 + r0 * wx[3] + r1 * wy[3] + r2 * wz[3];
            float z4 = f4 + r0 * wx[4] + r1 * wy[4] + r2 * wz[4];
            float z5 = f5 + r0 * wx[5] + r1 * wy[5] + r2 * wz[5];
            float z6 = f6 + r0 * wx[6] + r1 * wy[6] + r2 * wz[6];
            float z7 = f7 + r0 * wx[7] + r1 * wy[7] + r2 * wz[7];
            acc[0] += LEAKY(z0); acc[1] += LEAKY(z1);
            acc[2] += LEAKY(z2); acc[3] += LEAKY(z3);
            acc[4] += LEAKY(z4); acc[5] += LEAKY(z5);
            acc[6] += LEAKY(z6); acc[7] += LEAKY(z7);
        }
        if (t < m) {   // tail: up to 3 edges, predicated per-quarter
            const int e = t + quarter;       // <= 63 always
            const int   s  = __shfl(idx, e);
            const float r0 = __shfl(rx, e);
            const float r1 = __shfl(ry, e);
            const float r2 = __shfl(rz, e);
            if (e < m) {
                const uint4 y = *(const uint4*)(Yb + (size_t)s * 128 + cl);
                const float f0 = __uint_as_float((y.x & 0xffffu) << 16);
                const float f1 = __uint_as_float(y.x & 0xffff0000u);
                const float f2 = __uint_as_float((y.y & 0xffffu) << 16);
                const float f3 = __uint_as_float(y.y & 0xffff0000u);
                const float f4 = __uint_as_float((y.z & 0xffffu) << 16);
                const float f5 = __uint_as_float(y.z & 0xffff0000u);
                const float f6 = __uint_as_float((y.w & 0xffffu) << 16);
                const float f7 = __uint_as_float(y.w & 0xffff0000u);
                float z0 = f0 + r0 * wx[0] + r1 * wy[0] + r2 * wz[0];
                float z1 = f1 + r0 * wx[1] + r1 * wy[1] + r2 * wz[1];
                float z2 = f2 + r0 * wx[2] + r1 * wy[2] + r2 * wz[2];
                float z3 = f3 + r0 * wx[3] + r1 * wy[3] + r2 * wz[3];
                float z4 = f4 + r0 * wx[4] + r1 * wy[4] + r2 * wz[4];
                float z5 = f5 + r0 * wx[5] + r1 * wy[5] + r2 * wz[5];
                float z6 = f6 + r0 * wx[6] + r1 * wy[6] + r2 * wz[6];
                float z7 = f7 + r0 * wx[7] + r1 * wy[7] + r2 * wz[7];
                acc[0] += LEAKY(z0); acc[1] += LEAKY(z1);
                acc[2] += LEAKY(z2); acc[3] += LEAKY(z3);
                acc[4] += LEAKY(z4); acc[5] += LEAKY(z5);
                acc[6] += LEAKY(z6); acc[7] += LEAKY(z7);
            }
        }
    }

    #pragma unroll
    for (int j = 0; j < 8; ++j) {
        acc[j] += __shfl_xor(acc[j], 16);
        acc[j] += __shfl_xor(acc[j], 32);
    }
    if (quarter == 0) {
        *(float4*)(aggr + (size_t)d * 128 + cl) =
            make_float4(acc[0], acc[1], acc[2], acc[3]);
        *(float4*)(aggr + (size_t)d * 128 + cl + 4) =
            make_float4(acc[4], acc[5], acc[6], acc[7]);
    }
}

// ---------------- gemm_g (MFMA): out = leaky(aggr@g_w1+b1)@g_w2 + b2 + x (in-place aggr==out) ----
__global__ __launch_bounds__(256) void gemm_g(
    const float* __restrict__ aggr,
    const unsigned short* __restrict__ G1t, const float* __restrict__ g_b1,
    const unsigned short* __restrict__ G2t, const float* __restrict__ g_b2,
    const float* __restrict__ x,
    float* __restrict__ out, int N)
{
    __shared__ unsigned short Ts[64][136];   // +8 pad -> 2-way bank access on b128 reads

    const int lane = threadIdx.x & 63;
    const int wave = threadIdx.x >> 6;
    const int quad = lane >> 4;
    const int l16  = lane & 15;
    const int row0 = blockIdx.x * 64 + wave * 16;

    // phase 1: A from fp32 aggr
    bf16x8 a[4];
    {
        const int row = row0 + l16;
        if (row < N) {
            const float* ap = aggr + (size_t)row * 128 + quad * 8;
            #pragma unroll
            for (int kc = 0; kc < 4; ++kc) a[kc] = cvt8(ap + kc * 32);
        } else {
            #pragma unroll
            for (int kc = 0; kc < 4; ++kc) a[kc] = zero_ab();
        }
    }

    f32x4 acc[8];
    #pragma unroll
    for (int nt = 0; nt < 8; ++nt) acc[nt] = (f32x4){0.f, 0.f, 0.f, 0.f};

    #pragma unroll
    for (int nt = 0; nt < 8; ++nt) {
        const unsigned short* wp = G1t + (size_t)(nt * 16 + l16) * 128 + quad * 8;
        #pragma unroll
        for (int kc = 0; kc < 4; ++kc) {
            const bf16x8 b = *(const bf16x8*)(wp + kc * 32);
            acc[nt] = __builtin_amdgcn_mfma_f32_16x16x32_bf16(a[kc], b, acc[nt], 0, 0, 0);
        }
    }

    // T = leaky(acc + b1) -> bf16 LDS (C layout: col=nt*16+l16, row=wave*16+quad*4+reg)
    #pragma unroll
    for (int nt = 0; nt < 8; ++nt) {
        const int col = nt * 16 + l16;
        const float b1 = g_b1[col];
        #pragma unroll
        for (int reg = 0; reg < 4; ++reg) {
            float t = acc[nt][reg] + b1;
            t = LEAKY(t);
            Ts[wave * 16 + quad * 4 + reg][col] = f2bf(t);
        }
    }
    __syncthreads();

    // phase 2: A from LDS, B = G2t
    bf16x8 a2[4];
    {
        const unsigned short* tp = &Ts[wave * 16 + l16][quad * 8];
        #pragma unroll
        for (int kc = 0; kc < 4; ++kc) a2[kc] = *(const bf16x8*)(tp + kc * 32);
    }

    f32x4 acc2[8];
    #pragma unroll
    for (int nt = 0; nt < 8; ++nt) acc2[nt] = (f32x4){0.f, 0.f, 0.f, 0.f};

    #pragma unroll
    for (int nt = 0; nt < 8; ++nt) {
        const unsigned short* wp = G2t + (size_t)(nt * 16 + l16) * 128 + quad * 8;
        #pragma unroll
        for (int kc = 0; kc < 4; ++kc) {
            const bf16x8 b = *(const bf16x8*)(wp + kc * 32);
            acc2[nt] = __builtin_amdgcn_mfma_f32_16x16x32_bf16(a2[kc], b, acc2[nt], 0, 0, 0);
        }
    }

    // epilogue: + b2 + x
    #pragma unroll
    for (int nt = 0; nt < 8; ++nt) {
        const int col = nt * 16 + l16;
        const float b2 = g_b2[col];
        #pragma unroll
        for (int reg = 0; reg < 4; ++reg) {
            const int grow = row0 + quad * 4 + reg;
            if (grow < N)
                out[(size_t)grow * 128 + col] =
                    acc2[nt][reg] + b2 + x[(size_t)grow * 128 + col];
        }
    }
}

// ---------------- launch ----------------
extern "C" void kernel_launch(void* const* d_in, const int* in_sizes, int n_in,
                              void* d_out, int out_size, void* d_ws, size_t ws_size,
                              hipStream_t stream) {
    const float* x    = (const float*)d_in[0];
    const float* pos  = (const float*)d_in[1];
    const int*   ei   = (const int*)d_in[2];
    const float* h_w1 = (const float*)d_in[3];
    const float* h_b1 = (const float*)d_in[4];
    const float* h_w2 = (const float*)d_in[5];
    const float* h_b2 = (const float*)d_in[6];
    const float* f_w  = (const float*)d_in[7];   // [131,128]
    const float* f_b  = (const float*)d_in[8];
    const float* g_w1 = (const float*)d_in[9];
    const float* g_b1 = (const float*)d_in[10];
    const float* g_w2 = (const float*)d_in[11];
    const float* g_b2 = (const float*)d_in[12];
    float* out = (float*)d_out;

    const int N = in_sizes[0] / 128;
    const int E = in_sizes[2] / 2;

    // ws (~14.8 MB): delta[N*3]f32 | Yb[N*128]u16 | counts[N] | offs[N] | bsums[1024] |
    //                srcs[E]u16 | Wht/Wft/G1t/G2t [128*128]u16 each
    float* delta          = (float*)d_ws;
    unsigned short* Yb    = (unsigned short*)(delta + (size_t)N * 3);
    int* counts           = (int*)(Yb + (size_t)N * 128);
    int* offs             = counts + N;
    int* bsums            = offs + N;
    unsigned short* srcs  = (unsigned short*)(bsums + 1024);
    unsigned short* Wht   = srcs + (size_t)E;
    unsigned short* Wft   = Wht + 128 * 128;
    unsigned short* G1t   = Wft + 128 * 128;
    unsigned short* G2t   = G1t + 128 * 128;
    float* aggr           = out;

    const int tile_blocks = (N + 63) / 64;
    const int hist_blocks = (E + 255) / 256;
    const int B = (N + 1023) / 1024;

    hipMemsetAsync(counts, 0, (size_t)N * sizeof(int), stream);

    prep_weights<<<128, 128, 0, stream>>>(h_w1, f_w, g_w1, g_w2, Wht, Wft, G1t, G2t);

    node_pre_hist<<<tile_blocks + hist_blocks, 256, 0, stream>>>(
        x, Wht, h_b1, h_w2, h_b2, Wft, f_b, delta, Yb, N,
        ei, counts, E, tile_blocks);

    scan_local<<<B, 256, 0, stream>>>(counts, offs, bsums, N);
    scan_top<<<1, 256, 0, stream>>>(bsums, B);
    scan_fixup<<<B, 256, 0, stream>>>(offs, bsums, N);

    scatter_kernel<<<hist_blocks, 256, 0, stream>>>(ei, offs, srcs, E);

    aggregate_kernel<<<(N + 3) / 4, 256, 0, stream>>>(
        srcs, offs, counts, pos, delta, Yb, f_w, aggr, N);

    gemm_g<<<tile_blocks, 256, 0, stream>>>(aggr, G1t, g_b1, G2t, g_b2, x, out, N);
}

// Round 10
// 276.658 us; speedup vs baseline: 1.4301x; 1.1291x over previous
//
#include <hip/hip_runtime.h>
#include <hip/hip_bf16.h>
#include <math.h>

// GNNConv rewrites:
//  (1) msg @ f_w = rel @ f_w[0:3] + x[src] @ f_w[3:]  -> per-node Yb (bf16) instead of per-edge GEMM
//  (2) dst-sorted aggregation (ushort src indices), wave-per-dst, zero atomics
//  (3) MFMA GEMMs with block-level LDS weight staging (r10: per-wave global B reads were
//      the 78us latency wall -- every wave re-read 64KB of weights from L2; now staged once
//      per block, ds_read_b128 thereafter). hist de-fused (r9: fusion cost ~25us).
//  (4) aggregate: 4 edges/iter (quarter-wave, uint4 = 8 bf16/lane)

typedef __attribute__((ext_vector_type(8))) short bf16x8;
typedef __attribute__((ext_vector_type(4))) float f32x4;

#define LEAKY(v) ((v) >= 0.0f ? (v) : 0.01f * (v))

static __device__ __forceinline__ unsigned short f2bf(float f) {
    unsigned u = __float_as_uint(f);
    u = (u + 0x7fffu + ((u >> 16) & 1u)) >> 16;   // RNE
    return (unsigned short)u;
}

union ABu { unsigned short u[8]; bf16x8 v; };

static __device__ __forceinline__ bf16x8 cvt8(const float* __restrict__ p) {
    ABu r;
    const float4 v0 = *(const float4*)p;
    const float4 v1 = *(const float4*)(p + 4);
    r.u[0] = f2bf(v0.x); r.u[1] = f2bf(v0.y); r.u[2] = f2bf(v0.z); r.u[3] = f2bf(v0.w);
    r.u[4] = f2bf(v1.x); r.u[5] = f2bf(v1.y); r.u[6] = f2bf(v1.z); r.u[7] = f2bf(v1.w);
    return r.v;
}

static __device__ __forceinline__ bf16x8 zero_ab() {
    ABu r;
    #pragma unroll
    for (int i = 0; i < 8; ++i) r.u[i] = 0;
    return r.v;
}

// stage a 128x128 bf16 matrix (row-major, stride 128) into LDS [128][136] (16B-aligned rows)
static __device__ __forceinline__ void stage_weight(
    const unsigned short* __restrict__ src, unsigned short (*dst)[136], int tid)
{
    #pragma unroll
    for (int it = 0; it < 8; ++it) {
        const int c   = it * 256 + tid;      // 0..2047 uint4 chunks
        const int row = c >> 4;              // 16 chunks per row
        const int col = (c & 15) * 8;
        *(uint4*)&dst[row][col] = *(const uint4*)(src + row * 128 + col);
    }
}

// ---------------- weight prep: bf16 transposed copies (W^T[n][k]) ----------------
__global__ __launch_bounds__(128) void prep_weights(
    const float* __restrict__ h_w1, const float* __restrict__ f_w,
    const float* __restrict__ g_w1, const float* __restrict__ g_w2,
    unsigned short* __restrict__ Wht, unsigned short* __restrict__ Wft,
    unsigned short* __restrict__ G1t, unsigned short* __restrict__ G2t)
{
    const int j = blockIdx.x;      // output channel (row of W^T)
    const int k = threadIdx.x;     // k index
    Wht[j * 128 + k] = f2bf(h_w1[(size_t)k * 128 + j]);
    Wft[j * 128 + k] = f2bf(f_w[(size_t)(3 + k) * 128 + j]);
    G1t[j * 128 + k] = f2bf(g_w1[(size_t)k * 128 + j]);
    G2t[j * 128 + k] = f2bf(g_w2[(size_t)k * 128 + j]);
}

// ---------------- node_pre (MFMA, LDS-staged weights, two phases) ----------------
// delta = tanh(leaky(x@h_w1+b1)@h_w2+b2); Yb = bf16(x@f_w[3:]+f_b). 64 rows/block.
__global__ __launch_bounds__(256) void node_pre(
    const float* __restrict__ x,
    const unsigned short* __restrict__ Wht, const float* __restrict__ h_b1,
    const float* __restrict__ h_w2, const float* __restrict__ h_b2,
    const unsigned short* __restrict__ Wft, const float* __restrict__ f_b,
    float* __restrict__ delta, unsigned short* __restrict__ Yb, int N)
{
    __shared__ unsigned short Ws[128][136];   // one weight matrix per phase (~34 KB)
    __shared__ float cb[128][6];              // h_b1 | f_b | h_w2[0..2]

    const int tid  = threadIdx.x;
    const int lane = tid & 63;
    const int wave = tid >> 6;
    const int quad = lane >> 4;
    const int l16  = lane & 15;
    const int row0 = blockIdx.x * 64 + wave * 16;

    if (tid < 128) {
        cb[tid][0] = h_b1[tid];
        cb[tid][1] = f_b[tid];
        cb[tid][2] = h_w2[tid * 3 + 0];
        cb[tid][3] = h_w2[tid * 3 + 1];
        cb[tid][4] = h_w2[tid * 3 + 2];
    }
    stage_weight(Wht, Ws, tid);

    // A-fragments: A[m=l16][k=quad*8+j], 4 k-chunks of 32 (load before first barrier)
    bf16x8 a[4];
    {
        const int row = row0 + l16;
        if (row < N) {
            const float* xp = x + (size_t)row * 128 + quad * 8;
            #pragma unroll
            for (int kc = 0; kc < 4; ++kc) a[kc] = cvt8(xp + kc * 32);
        } else {
            #pragma unroll
            for (int kc = 0; kc < 4; ++kc) a[kc] = zero_ab();
        }
    }
    __syncthreads();

    // phase 1: acch = x @ h_w1  (B from LDS)
    f32x4 acch[8];
    #pragma unroll
    for (int nt = 0; nt < 8; ++nt) acch[nt] = (f32x4){0.f, 0.f, 0.f, 0.f};
    #pragma unroll
    for (int nt = 0; nt < 8; ++nt) {
        const unsigned short* wp = &Ws[nt * 16 + l16][quad * 8];
        #pragma unroll
        for (int kc = 0; kc < 4; ++kc) {
            const bf16x8 b = *(const bf16x8*)(wp + kc * 32);
            acch[nt] = __builtin_amdgcn_mfma_f32_16x16x32_bf16(a[kc], b, acch[nt], 0, 0, 0);
        }
    }

    __syncthreads();
    stage_weight(Wft, Ws, tid);
    __syncthreads();

    // phase 2: accf = x @ f_w[3:]
    f32x4 accf[8];
    #pragma unroll
    for (int nt = 0; nt < 8; ++nt) accf[nt] = (f32x4){0.f, 0.f, 0.f, 0.f};
    #pragma unroll
    for (int nt = 0; nt < 8; ++nt) {
        const unsigned short* wp = &Ws[nt * 16 + l16][quad * 8];
        #pragma unroll
        for (int kc = 0; kc < 4; ++kc) {
            const bf16x8 b = *(const bf16x8*)(wp + kc * 32);
            accf[nt] = __builtin_amdgcn_mfma_f32_16x16x32_bf16(a[kc], b, accf[nt], 0, 0, 0);
        }
    }

    // Epilogue. C/D layout: col = nt*16 + l16, local row = quad*4 + reg.
    float p[4][3];
    #pragma unroll
    for (int r = 0; r < 4; ++r) { p[r][0] = 0.f; p[r][1] = 0.f; p[r][2] = 0.f; }

    #pragma unroll
    for (int nt = 0; nt < 8; ++nt) {
        const int col = nt * 16 + l16;
        const float b1  = cb[col][0];
        const float fb  = cb[col][1];
        const float w20 = cb[col][2];
        const float w21 = cb[col][3];
        const float w22 = cb[col][4];
        #pragma unroll
        for (int reg = 0; reg < 4; ++reg) {
            const int grow = row0 + quad * 4 + reg;
            float h = acch[nt][reg] + b1;
            h = LEAKY(h);
            p[reg][0] += h * w20;
            p[reg][1] += h * w21;
            p[reg][2] += h * w22;
            if (grow < N)
                Yb[(size_t)grow * 128 + col] = f2bf(accf[nt][reg] + fb);
        }
    }

    // reduce p across the 16 l16 lanes (within quad)
    #pragma unroll
    for (int reg = 0; reg < 4; ++reg)
        #pragma unroll
        for (int c = 0; c < 3; ++c) {
            float v = p[reg][c];
            v += __shfl_down(v, 8);
            v += __shfl_down(v, 4);
            v += __shfl_down(v, 2);
            v += __shfl_down(v, 1);
            p[reg][c] = v;
        }

    if (l16 == 0) {
        #pragma unroll
        for (int reg = 0; reg < 4; ++reg) {
            const int grow = row0 + quad * 4 + reg;
            if (grow < N) {
                delta[(size_t)grow * 3 + 0] = tanhf(p[reg][0] + h_b2[0]);
                delta[(size_t)grow * 3 + 1] = tanhf(p[reg][1] + h_b2[1]);
                delta[(size_t)grow * 3 + 2] = tanhf(p[reg][2] + h_b2[2]);
            }
        }
    }
}

// ---------------- edge histogram (standalone) ----------------
__global__ __launch_bounds__(256) void hist_kernel(
    const int* __restrict__ ei, int* __restrict__ counts, int E)
{
    const int e = blockIdx.x * 256 + threadIdx.x;
    if (e < E) atomicAdd(&counts[ei[(size_t)E + e]], 1);
}

// ---------------- hierarchical scan (counts -> offs), 1024 elems/block ----------------
__global__ __launch_bounds__(256) void scan_local(
    const int* __restrict__ counts, int* __restrict__ offs,
    int* __restrict__ blocksums, int N)
{
    __shared__ int s[256];
    const int tid  = threadIdx.x;
    const int base = blockIdx.x * 1024 + tid * 4;
    int v[4], sum = 0;
    #pragma unroll
    for (int j = 0; j < 4; ++j) {
        v[j] = (base + j < N) ? counts[base + j] : 0;
        sum += v[j];
    }
    s[tid] = sum;
    __syncthreads();
    for (int d = 1; d < 256; d <<= 1) {
        int t = (tid >= d) ? s[tid - d] : 0;
        __syncthreads();
        s[tid] += t;
        __syncthreads();
    }
    int run = s[tid] - sum;
    #pragma unroll
    for (int j = 0; j < 4; ++j) {
        if (base + j < N) offs[base + j] = run;
        run += v[j];
    }
    if (tid == 255) blocksums[blockIdx.x] = s[255];
}

__global__ __launch_bounds__(256) void scan_top(
    int* __restrict__ blocksums, int B)
{
    __shared__ int s[256];
    const int tid = threadIdx.x;
    int v[4], sum = 0;
    const int base = tid * 4;
    #pragma unroll
    for (int j = 0; j < 4; ++j) {
        v[j] = (base + j < B) ? blocksums[base + j] : 0;
        sum += v[j];
    }
    s[tid] = sum;
    __syncthreads();
    for (int d = 1; d < 256; d <<= 1) {
        int t = (tid >= d) ? s[tid - d] : 0;
        __syncthreads();
        s[tid] += t;
        __syncthreads();
    }
    int run = s[tid] - sum;
    #pragma unroll
    for (int j = 0; j < 4; ++j) {
        if (base + j < B) blocksums[base + j] = run;
        run += v[j];
    }
}

__global__ __launch_bounds__(256) void scan_fixup(
    int* __restrict__ offs, const int* __restrict__ blocksums, int N)
{
    const int i = blockIdx.x * 1024 + threadIdx.x * 4;
    const int add = blocksums[blockIdx.x];
    #pragma unroll
    for (int j = 0; j < 4; ++j)
        if (i + j < N) offs[i + j] += add;
}

// ---------------- scatter src indices into dst-sorted order ----------------
__global__ __launch_bounds__(256) void scatter_kernel(
    const int* __restrict__ ei, int* __restrict__ offs,
    unsigned short* __restrict__ srcs_sorted, int E)
{
    const int e = blockIdx.x * 256 + threadIdx.x;
    if (e < E) {
        const int src = ei[e];
        const int dst = ei[(size_t)E + e];
        const int p = atomicAdd(&offs[dst], 1);
        srcs_sorted[p] = (unsigned short)src;   // N < 65536
    }
}

// ---------------- aggregation: wave-per-dst, 4 edges/iter (quarter-wave each) ----------------
__global__ __launch_bounds__(256) void aggregate_kernel(
    const unsigned short* __restrict__ srcs_sorted,
    const int* __restrict__ offs_end,      // start + count
    const int* __restrict__ counts,
    const float* __restrict__ pos,         // [N,3]
    const float* __restrict__ delta,       // [N,3]
    const unsigned short* __restrict__ Yb, // [N,128] bf16
    const float* __restrict__ fw3,         // [3][128]
    float* __restrict__ aggr,              // [N,128] = d_out
    int N)
{
    const int lane = threadIdx.x & 63;
    const int d = blockIdx.x * 4 + (threadIdx.x >> 6);
    if (d >= N) return;

    const int quarter = lane >> 4;
    const int cl      = (lane & 15) * 8;

    float wx[8], wy[8], wz[8];
    #pragma unroll
    for (int j = 0; j < 8; ++j) {
        wx[j] = fw3[cl + j];
        wy[j] = fw3[128 + cl + j];
        wz[j] = fw3[256 + cl + j];
    }

    const int len   = counts[d];
    const int start = offs_end[d] - len;
    const float q0 = delta[(size_t)d * 3 + 0] - pos[(size_t)d * 3 + 0];
    const float q1 = delta[(size_t)d * 3 + 1] - pos[(size_t)d * 3 + 1];
    const float q2 = delta[(size_t)d * 3 + 2] - pos[(size_t)d * 3 + 2];

    float acc[8] = {0.f, 0.f, 0.f, 0.f, 0.f, 0.f, 0.f, 0.f};

    for (int chunk = 0; chunk < len; chunk += 64) {
        const int m = min(64, len - chunk);
        int idx = 0; float rx = 0.f, ry = 0.f, rz = 0.f;
        if (lane < m) {
            idx = srcs_sorted[start + chunk + lane];
            rx = pos[(size_t)idx * 3 + 0] + q0;
            ry = pos[(size_t)idx * 3 + 1] + q1;
            rz = pos[(size_t)idx * 3 + 2] + q2;
        }
        int t = 0;
        #pragma unroll 2
        for (; t + 4 <= m; t += 4) {
            const int e = t + quarter;
            const int   s  = __shfl(idx, e);
            const float r0 = __shfl(rx, e);
            const float r1 = __shfl(ry, e);
            const float r2 = __shfl(rz, e);
            const uint4 y = *(const uint4*)(Yb + (size_t)s * 128 + cl);
            const float f0 = __uint_as_float((y.x & 0xffffu) << 16);
            const float f1 = __uint_as_float(y.x & 0xffff0000u);
            const float f2 = __uint_as_float((y.y & 0xffffu) << 16);
            const float f3 = __uint_as_float(y.y & 0xffff0000u);
            const float f4 = __uint_as_float((y.z & 0xffffu) << 16);
            const float f5 = __uint_as_float(y.z & 0xffff0000u);
            const float f6 = __uint_as_float((y.w & 0xffffu) << 16);
            const float f7 = __uint_as_float(y.w & 0xffff0000u);
            float z0 = f0 + r0 * wx[0] + r1 * wy[0] + r2 * wz[0];
            float z1 = f1 + r0 * wx[1] + r1 * wy[1] + r2 * wz[1];
            float z2 = f2 + r0 * wx[2] + r1 * wy[2] + r2 * wz[2];
            float z3 = f3 + r0 * wx[3] + r1 * wy[3] + r2 * wz[3];
            float z4 = f4 + r0 * wx[4] + r1 * wy[4] + r2 * wz[4];
            float z5 = f5 + r0 * wx[5] + r1 * wy[5] + r2 * wz[5];
            float z6 = f6 + r0 * wx[6] + r1 * wy[6] + r2 * wz[6];
            float z7 = f7 + r0 * wx[7] + r1 * wy[7] + r2 * wz[7];
            acc[0] += LEAKY(z0); acc[1] += LEAKY(z1);
            acc[2] += LEAKY(z2); acc[3] += LEAKY(z3);
            acc[4] += LEAKY(z4); acc[5] += LEAKY(z5);
            acc[6] += LEAKY(z6); acc[7] += LEAKY(z7);
        }
        if (t < m) {   // tail: up to 3 edges, predicated per-quarter
            const int e = t + quarter;       // <= 63 always
            const int   s  = __shfl(idx, e);
            const float r0 = __shfl(rx, e);
            const float r1 = __shfl(ry, e);
            const float r2 = __shfl(rz, e);
            if (e < m) {
                const uint4 y = *(const uint4*)(Yb + (size_t)s * 128 + cl);
                const float f0 = __uint_as_float((y.x & 0xffffu) << 16);
                const float f1 = __uint_as_float(y.x & 0xffff0000u);
                const float f2 = __uint_as_float((y.y & 0xffffu) << 16);
                const float f3 = __uint_as_float(y.y & 0xffff0000u);
                const float f4 = __uint_as_float((y.z & 0xffffu) << 16);
                const float f5 = __uint_as_float(y.z & 0xffff0000u);
                const float f6 = __uint_as_float((y.w & 0xffffu) << 16);
                const float f7 = __uint_as_float(y.w & 0xffff0000u);
                float z0 = f0 + r0 * wx[0] + r1 * wy[0] + r2 * wz[0];
                float z1 = f1 + r0 * wx[1] + r1 * wy[1] + r2 * wz[1];
                float z2 = f2 + r0 * wx[2] + r1 * wy[2] + r2 * wz[2];
                float z3 = f3 + r0 * wx[3] + r1 * wy[3] + r2 * wz[3];
                float z4 = f4 + r0 * wx[4] + r1 * wy[4] + r2 * wz[4];
                float z5 = f5 + r0 * wx[5] + r1 * wy[5] + r2 * wz[5];
                float z6 = f6 + r0 * wx[6] + r1 * wy[6] + r2 * wz[6];
                float z7 = f7 + r0 * wx[7] + r1 * wy[7] + r2 * wz[7];
                acc[0] += LEAKY(z0); acc[1] += LEAKY(z1);
                acc[2] += LEAKY(z2); acc[3] += LEAKY(z3);
                acc[4] += LEAKY(z4); acc[5] += LEAKY(z5);
                acc[6] += LEAKY(z6); acc[7] += LEAKY(z7);
            }
        }
    }

    #pragma unroll
    for (int j = 0; j < 8; ++j) {
        acc[j] += __shfl_xor(acc[j], 16);
        acc[j] += __shfl_xor(acc[j], 32);
    }
    if (quarter == 0) {
        *(float4*)(aggr + (size_t)d * 128 + cl) =
            make_float4(acc[0], acc[1], acc[2], acc[3]);
        *(float4*)(aggr + (size_t)d * 128 + cl + 4) =
            make_float4(acc[4], acc[5], acc[6], acc[7]);
    }
}

// ---------------- gemm_g (MFMA, LDS-staged weights): out = leaky(aggr@g_w1+b1)@g_w2+b2+x ----
__global__ __launch_bounds__(256) void gemm_g(
    const float* __restrict__ aggr,
    const unsigned short* __restrict__ G1t, const float* __restrict__ g_b1,
    const unsigned short* __restrict__ G2t, const float* __restrict__ g_b2,
    const float* __restrict__ x,
    float* __restrict__ out, int N)
{
    __shared__ unsigned short Ws[128][136];  // weight matrix per phase (~34 KB)
    __shared__ unsigned short Ts[64][136];   // intermediate T (bf16, ~17 KB)

    const int tid  = threadIdx.x;
    const int lane = tid & 63;
    const int wave = tid >> 6;
    const int quad = lane >> 4;
    const int l16  = lane & 15;
    const int row0 = blockIdx.x * 64 + wave * 16;

    stage_weight(G1t, Ws, tid);

    // phase 1: A from fp32 aggr (load before barrier)
    bf16x8 a[4];
    {
        const int row = row0 + l16;
        if (row < N) {
            const float* ap = aggr + (size_t)row * 128 + quad * 8;
            #pragma unroll
            for (int kc = 0; kc < 4; ++kc) a[kc] = cvt8(ap + kc * 32);
        } else {
            #pragma unroll
            for (int kc = 0; kc < 4; ++kc) a[kc] = zero_ab();
        }
    }
    __syncthreads();

    f32x4 acc[8];
    #pragma unroll
    for (int nt = 0; nt < 8; ++nt) acc[nt] = (f32x4){0.f, 0.f, 0.f, 0.f};
    #pragma unroll
    for (int nt = 0; nt < 8; ++nt) {
        const unsigned short* wp = &Ws[nt * 16 + l16][quad * 8];
        #pragma unroll
        for (int kc = 0; kc < 4; ++kc) {
            const bf16x8 b = *(const bf16x8*)(wp + kc * 32);
            acc[nt] = __builtin_amdgcn_mfma_f32_16x16x32_bf16(a[kc], b, acc[nt], 0, 0, 0);
        }
    }

    // T = leaky(acc + b1) -> bf16 LDS (C layout: col=nt*16+l16, row=wave*16+quad*4+reg)
    #pragma unroll
    for (int nt = 0; nt < 8; ++nt) {
        const int col = nt * 16 + l16;
        const float b1 = g_b1[col];
        #pragma unroll
        for (int reg = 0; reg < 4; ++reg) {
            float t = acc[nt][reg] + b1;
            t = LEAKY(t);
            Ts[wave * 16 + quad * 4 + reg][col] = f2bf(t);
        }
    }
    __syncthreads();          // Ts complete + all phase-1 Ws reads done
    stage_weight(G2t, Ws, tid);
    __syncthreads();

    // phase 2: A from Ts, B from re-staged Ws
    bf16x8 a2[4];
    {
        const unsigned short* tp = &Ts[wave * 16 + l16][quad * 8];
        #pragma unroll
        for (int kc = 0; kc < 4; ++kc) a2[kc] = *(const bf16x8*)(tp + kc * 32);
    }

    f32x4 acc2[8];
    #pragma unroll
    for (int nt = 0; nt < 8; ++nt) acc2[nt] = (f32x4){0.f, 0.f, 0.f, 0.f};
    #pragma unroll
    for (int nt = 0; nt < 8; ++nt) {
        const unsigned short* wp = &Ws[nt * 16 + l16][quad * 8];
        #pragma unroll
        for (int kc = 0; kc < 4; ++kc) {
            const bf16x8 b = *(const bf16x8*)(wp + kc * 32);
            acc2[nt] = __builtin_amdgcn_mfma_f32_16x16x32_bf16(a2[kc], b, acc2[nt], 0, 0, 0);
        }
    }

    // epilogue: + b2 + x
    #pragma unroll
    for (int nt = 0; nt < 8; ++nt) {
        const int col = nt * 16 + l16;
        const float b2 = g_b2[col];
        #pragma unroll
        for (int reg = 0; reg < 4; ++reg) {
            const int grow = row0 + quad * 4 + reg;
            if (grow < N)
                out[(size_t)grow * 128 + col] =
                    acc2[nt][reg] + b2 + x[(size_t)grow * 128 + col];
        }
    }
}

// ---------------- launch ----------------
extern "C" void kernel_launch(void* const* d_in, const int* in_sizes, int n_in,
                              void* d_out, int out_size, void* d_ws, size_t ws_size,
                              hipStream_t stream) {
    const float* x    = (const float*)d_in[0];
    const float* pos  = (const float*)d_in[1];
    const int*   ei   = (const int*)d_in[2];
    const float* h_w1 = (const float*)d_in[3];
    const float* h_b1 = (const float*)d_in[4];
    const float* h_w2 = (const float*)d_in[5];
    const float* h_b2 = (const float*)d_in[6];
    const float* f_w  = (const float*)d_in[7];   // [131,128]
    const float* f_b  = (const float*)d_in[8];
    const float* g_w1 = (const float*)d_in[9];
    const float* g_b1 = (const float*)d_in[10];
    const float* g_w2 = (const float*)d_in[11];
    const float* g_b2 = (const float*)d_in[12];
    float* out = (float*)d_out;

    const int N = in_sizes[0] / 128;
    const int E = in_sizes[2] / 2;

    // ws (~14.8 MB): delta[N*3]f32 | Yb[N*128]u16 | counts[N] | offs[N] | bsums[1024] |
    //                srcs[E]u16 | Wht/Wft/G1t/G2t [128*128]u16 each
    float* delta          = (float*)d_ws;
    unsigned short* Yb    = (unsigned short*)(delta + (size_t)N * 3);
    int* counts           = (int*)(Yb + (size_t)N * 128);
    int* offs             = counts + N;
    int* bsums            = offs + N;
    unsigned short* srcs  = (unsigned short*)(bsums + 1024);
    unsigned short* Wht   = srcs + (size_t)E;
    unsigned short* Wft   = Wht + 128 * 128;
    unsigned short* G1t   = Wft + 128 * 128;
    unsigned short* G2t   = G1t + 128 * 128;
    float* aggr           = out;

    const int tile_blocks = (N + 63) / 64;
    const int hist_blocks = (E + 255) / 256;
    const int B = (N + 1023) / 1024;

    hipMemsetAsync(counts, 0, (size_t)N * sizeof(int), stream);

    prep_weights<<<128, 128, 0, stream>>>(h_w1, f_w, g_w1, g_w2, Wht, Wft, G1t, G2t);

    hist_kernel<<<hist_blocks, 256, 0, stream>>>(ei, counts, E);

    node_pre<<<tile_blocks, 256, 0, stream>>>(x, Wht, h_b1, h_w2, h_b2, Wft, f_b,
                                              delta, Yb, N);

    scan_local<<<B, 256, 0, stream>>>(counts, offs, bsums, N);
    scan_top<<<1, 256, 0, stream>>>(bsums, B);
    scan_fixup<<<B, 256, 0, stream>>>(offs, bsums, N);

    scatter_kernel<<<hist_blocks, 256, 0, stream>>>(ei, offs, srcs, E);

    aggregate_kernel<<<(N + 3) / 4, 256, 0, stream>>>(
        srcs, offs, counts, pos, delta, Yb, f_w, aggr, N);

    gemm_g<<<tile_blocks, 256, 0, stream>>>(aggr, G1t, g_b1, G2t, g_b2, x, out, N);
}

// Round 11
// 272.173 us; speedup vs baseline: 1.4537x; 1.0165x over previous
//
#include <hip/hip_runtime.h>
#include <hip/hip_bf16.h>
#include <math.h>

// GNNConv rewrites:
//  (1) msg @ f_w = rel @ f_w[0:3] + x[src] @ f_w[3:]  -> per-node Yb instead of per-edge GEMM
//  (2) r11: further fold  z = Yb[s] + (pos[s]-pos[d]+delta[d])@fw3
//                           = Zb[s] + qd[d]   where Zb[s]=bf16(Yb[s]+pos[s]@fw3)  (node-level)
//                                             and   qd[d]=(delta[d]-pos[d])@fw3  (per-wave, once)
//      -> aggregate inner loop = one bf16x8 gather + add + leaky; no pos gathers, 1 shfl/edge
//  (3) dst-sorted aggregation (ushort srcs), wave-per-dst, zero atomics
//  (4) MFMA GEMMs with block-level LDS weight staging; hist standalone (r9: fusion regressed)

typedef __attribute__((ext_vector_type(8))) short bf16x8;
typedef __attribute__((ext_vector_type(4))) float f32x4;

#define LEAKY(v) ((v) >= 0.0f ? (v) : 0.01f * (v))

static __device__ __forceinline__ unsigned short f2bf(float f) {
    unsigned u = __float_as_uint(f);
    u = (u + 0x7fffu + ((u >> 16) & 1u)) >> 16;   // RNE
    return (unsigned short)u;
}

union ABu { unsigned short u[8]; bf16x8 v; };

static __device__ __forceinline__ bf16x8 cvt8(const float* __restrict__ p) {
    ABu r;
    const float4 v0 = *(const float4*)p;
    const float4 v1 = *(const float4*)(p + 4);
    r.u[0] = f2bf(v0.x); r.u[1] = f2bf(v0.y); r.u[2] = f2bf(v0.z); r.u[3] = f2bf(v0.w);
    r.u[4] = f2bf(v1.x); r.u[5] = f2bf(v1.y); r.u[6] = f2bf(v1.z); r.u[7] = f2bf(v1.w);
    return r.v;
}

static __device__ __forceinline__ bf16x8 zero_ab() {
    ABu r;
    #pragma unroll
    for (int i = 0; i < 8; ++i) r.u[i] = 0;
    return r.v;
}

// stage a 128x128 bf16 matrix (row-major, stride 128) into LDS [128][136]
static __device__ __forceinline__ void stage_weight(
    const unsigned short* __restrict__ src, unsigned short (*dst)[136], int tid)
{
    #pragma unroll
    for (int it = 0; it < 8; ++it) {
        const int c   = it * 256 + tid;
        const int row = c >> 4;
        const int col = (c & 15) * 8;
        *(uint4*)&dst[row][col] = *(const uint4*)(src + row * 128 + col);
    }
}

// ---------------- weight prep: bf16 transposed copies (W^T[n][k]) ----------------
__global__ __launch_bounds__(128) void prep_weights(
    const float* __restrict__ h_w1, const float* __restrict__ f_w,
    const float* __restrict__ g_w1, const float* __restrict__ g_w2,
    unsigned short* __restrict__ Wht, unsigned short* __restrict__ Wft,
    unsigned short* __restrict__ G1t, unsigned short* __restrict__ G2t)
{
    const int j = blockIdx.x;
    const int k = threadIdx.x;
    Wht[j * 128 + k] = f2bf(h_w1[(size_t)k * 128 + j]);
    Wft[j * 128 + k] = f2bf(f_w[(size_t)(3 + k) * 128 + j]);
    G1t[j * 128 + k] = f2bf(g_w1[(size_t)k * 128 + j]);
    G2t[j * 128 + k] = f2bf(g_w2[(size_t)k * 128 + j]);
}

// ---------------- node_pre (MFMA, LDS-staged weights) ----------------
// deltap = tanh(leaky(x@h_w1+b1)@h_w2+b2) - pos;  Zb = bf16(x@f_w[3:]+f_b + pos@fw3)
__global__ __launch_bounds__(256) void node_pre(
    const float* __restrict__ x, const float* __restrict__ pos,
    const unsigned short* __restrict__ Wht, const float* __restrict__ h_b1,
    const float* __restrict__ h_w2, const float* __restrict__ h_b2,
    const unsigned short* __restrict__ Wft, const float* __restrict__ f_b,
    const float* __restrict__ fw3,     // f_w rows 0..2: [3][128]
    float* __restrict__ deltap, unsigned short* __restrict__ Zb, int N)
{
    __shared__ unsigned short Ws[128][136];   // one weight matrix per phase (~34 KB)
    __shared__ float cb[128][8];              // h_b1 | f_b | h_w2*3 | fw3*3

    const int tid  = threadIdx.x;
    const int lane = tid & 63;
    const int wave = tid >> 6;
    const int quad = lane >> 4;
    const int l16  = lane & 15;
    const int row0 = blockIdx.x * 64 + wave * 16;

    if (tid < 128) {
        cb[tid][0] = h_b1[tid];
        cb[tid][1] = f_b[tid];
        cb[tid][2] = h_w2[tid * 3 + 0];
        cb[tid][3] = h_w2[tid * 3 + 1];
        cb[tid][4] = h_w2[tid * 3 + 2];
        cb[tid][5] = fw3[tid];
        cb[tid][6] = fw3[128 + tid];
        cb[tid][7] = fw3[256 + tid];
    }
    stage_weight(Wht, Ws, tid);

    // A-fragments
    bf16x8 a[4];
    {
        const int row = row0 + l16;
        if (row < N) {
            const float* xp = x + (size_t)row * 128 + quad * 8;
            #pragma unroll
            for (int kc = 0; kc < 4; ++kc) a[kc] = cvt8(xp + kc * 32);
        } else {
            #pragma unroll
            for (int kc = 0; kc < 4; ++kc) a[kc] = zero_ab();
        }
    }

    // pos for this lane's output rows (grow = row0 + quad*4 + reg)
    float px[4], py[4], pz[4];
    #pragma unroll
    for (int reg = 0; reg < 4; ++reg) {
        const int grow = row0 + quad * 4 + reg;
        const int gr = (grow < N) ? grow : 0;
        px[reg] = pos[(size_t)gr * 3 + 0];
        py[reg] = pos[(size_t)gr * 3 + 1];
        pz[reg] = pos[(size_t)gr * 3 + 2];
    }
    __syncthreads();

    // phase 1: acch = x @ h_w1
    f32x4 acch[8];
    #pragma unroll
    for (int nt = 0; nt < 8; ++nt) acch[nt] = (f32x4){0.f, 0.f, 0.f, 0.f};
    #pragma unroll
    for (int nt = 0; nt < 8; ++nt) {
        const unsigned short* wp = &Ws[nt * 16 + l16][quad * 8];
        #pragma unroll
        for (int kc = 0; kc < 4; ++kc) {
            const bf16x8 b = *(const bf16x8*)(wp + kc * 32);
            acch[nt] = __builtin_amdgcn_mfma_f32_16x16x32_bf16(a[kc], b, acch[nt], 0, 0, 0);
        }
    }

    __syncthreads();
    stage_weight(Wft, Ws, tid);
    __syncthreads();

    // phase 2: accf = x @ f_w[3:]
    f32x4 accf[8];
    #pragma unroll
    for (int nt = 0; nt < 8; ++nt) accf[nt] = (f32x4){0.f, 0.f, 0.f, 0.f};
    #pragma unroll
    for (int nt = 0; nt < 8; ++nt) {
        const unsigned short* wp = &Ws[nt * 16 + l16][quad * 8];
        #pragma unroll
        for (int kc = 0; kc < 4; ++kc) {
            const bf16x8 b = *(const bf16x8*)(wp + kc * 32);
            accf[nt] = __builtin_amdgcn_mfma_f32_16x16x32_bf16(a[kc], b, accf[nt], 0, 0, 0);
        }
    }

    // Epilogue. C/D layout: col = nt*16 + l16, local row = quad*4 + reg.
    float p[4][3];
    #pragma unroll
    for (int r = 0; r < 4; ++r) { p[r][0] = 0.f; p[r][1] = 0.f; p[r][2] = 0.f; }

    #pragma unroll
    for (int nt = 0; nt < 8; ++nt) {
        const int col = nt * 16 + l16;
        const float b1  = cb[col][0];
        const float fb  = cb[col][1];
        const float w20 = cb[col][2];
        const float w21 = cb[col][3];
        const float w22 = cb[col][4];
        const float wxc = cb[col][5];
        const float wyc = cb[col][6];
        const float wzc = cb[col][7];
        #pragma unroll
        for (int reg = 0; reg < 4; ++reg) {
            const int grow = row0 + quad * 4 + reg;
            float h = acch[nt][reg] + b1;
            h = LEAKY(h);
            p[reg][0] += h * w20;
            p[reg][1] += h * w21;
            p[reg][2] += h * w22;
            if (grow < N) {
                const float z = accf[nt][reg] + fb
                              + px[reg] * wxc + py[reg] * wyc + pz[reg] * wzc;
                Zb[(size_t)grow * 128 + col] = f2bf(z);
            }
        }
    }

    // reduce p across the 16 l16 lanes (within quad)
    #pragma unroll
    for (int reg = 0; reg < 4; ++reg)
        #pragma unroll
        for (int c = 0; c < 3; ++c) {
            float v = p[reg][c];
            v += __shfl_down(v, 8);
            v += __shfl_down(v, 4);
            v += __shfl_down(v, 2);
            v += __shfl_down(v, 1);
            p[reg][c] = v;
        }

    if (l16 == 0) {
        #pragma unroll
        for (int reg = 0; reg < 4; ++reg) {
            const int grow = row0 + quad * 4 + reg;
            if (grow < N) {
                deltap[(size_t)grow * 3 + 0] = tanhf(p[reg][0] + h_b2[0]) - px[reg];
                deltap[(size_t)grow * 3 + 1] = tanhf(p[reg][1] + h_b2[1]) - py[reg];
                deltap[(size_t)grow * 3 + 2] = tanhf(p[reg][2] + h_b2[2]) - pz[reg];
            }
        }
    }
}

// ---------------- edge histogram ----------------
__global__ __launch_bounds__(256) void hist_kernel(
    const int* __restrict__ ei, int* __restrict__ counts, int E)
{
    const int e = blockIdx.x * 256 + threadIdx.x;
    if (e < E) atomicAdd(&counts[ei[(size_t)E + e]], 1);
}

// ---------------- hierarchical scan (counts -> offs) ----------------
__global__ __launch_bounds__(256) void scan_local(
    const int* __restrict__ counts, int* __restrict__ offs,
    int* __restrict__ blocksums, int N)
{
    __shared__ int s[256];
    const int tid  = threadIdx.x;
    const int base = blockIdx.x * 1024 + tid * 4;
    int v[4], sum = 0;
    #pragma unroll
    for (int j = 0; j < 4; ++j) {
        v[j] = (base + j < N) ? counts[base + j] : 0;
        sum += v[j];
    }
    s[tid] = sum;
    __syncthreads();
    for (int d = 1; d < 256; d <<= 1) {
        int t = (tid >= d) ? s[tid - d] : 0;
        __syncthreads();
        s[tid] += t;
        __syncthreads();
    }
    int run = s[tid] - sum;
    #pragma unroll
    for (int j = 0; j < 4; ++j) {
        if (base + j < N) offs[base + j] = run;
        run += v[j];
    }
    if (tid == 255) blocksums[blockIdx.x] = s[255];
}

__global__ __launch_bounds__(256) void scan_top(
    int* __restrict__ blocksums, int B)
{
    __shared__ int s[256];
    const int tid = threadIdx.x;
    int v[4], sum = 0;
    const int base = tid * 4;
    #pragma unroll
    for (int j = 0; j < 4; ++j) {
        v[j] = (base + j < B) ? blocksums[base + j] : 0;
        sum += v[j];
    }
    s[tid] = sum;
    __syncthreads();
    for (int d = 1; d < 256; d <<= 1) {
        int t = (tid >= d) ? s[tid - d] : 0;
        __syncthreads();
        s[tid] += t;
        __syncthreads();
    }
    int run = s[tid] - sum;
    #pragma unroll
    for (int j = 0; j < 4; ++j) {
        if (base + j < B) blocksums[base + j] = run;
        run += v[j];
    }
}

__global__ __launch_bounds__(256) void scan_fixup(
    int* __restrict__ offs, const int* __restrict__ blocksums, int N)
{
    const int i = blockIdx.x * 1024 + threadIdx.x * 4;
    const int add = blocksums[blockIdx.x];
    #pragma unroll
    for (int j = 0; j < 4; ++j)
        if (i + j < N) offs[i + j] += add;
}

// ---------------- scatter src indices into dst-sorted order ----------------
__global__ __launch_bounds__(256) void scatter_kernel(
    const int* __restrict__ ei, int* __restrict__ offs,
    unsigned short* __restrict__ srcs_sorted, int E)
{
    const int e = blockIdx.x * 256 + threadIdx.x;
    if (e < E) {
        const int src = ei[e];
        const int dst = ei[(size_t)E + e];
        const int p = atomicAdd(&offs[dst], 1);
        srcs_sorted[p] = (unsigned short)src;   // N < 65536
    }
}

// ---------------- aggregation: aggr[d] = sum_e leaky(Zb[src_e] + qd) ----------------
// wave-per-dst, 4 edges/iter (quarter-wave). Per edge: 1 shfl + 1 uint4 gather + add/leaky.
__global__ __launch_bounds__(256) void aggregate_kernel(
    const unsigned short* __restrict__ srcs_sorted,
    const int* __restrict__ offs_end,      // start + count
    const int* __restrict__ counts,
    const float* __restrict__ deltap,      // [N,3] = delta - pos
    const unsigned short* __restrict__ Zb, // [N,128] bf16
    const float* __restrict__ fw3,         // [3][128]
    float* __restrict__ aggr,              // [N,128] = d_out
    int N)
{
    const int lane = threadIdx.x & 63;
    const int d = blockIdx.x * 4 + (threadIdx.x >> 6);
    if (d >= N) return;

    const int quarter = lane >> 4;
    const int cl      = (lane & 15) * 8;

    const float q0 = deltap[(size_t)d * 3 + 0];
    const float q1 = deltap[(size_t)d * 3 + 1];
    const float q2 = deltap[(size_t)d * 3 + 2];

    // qd[j] = q . fw3[:, cl+j]  (once per dst)
    float qd[8];
    #pragma unroll
    for (int j = 0; j < 8; ++j)
        qd[j] = q0 * fw3[cl + j] + q1 * fw3[128 + cl + j] + q2 * fw3[256 + cl + j];

    const int len   = counts[d];
    const int start = offs_end[d] - len;

    float acc[8] = {0.f, 0.f, 0.f, 0.f, 0.f, 0.f, 0.f, 0.f};

    for (int chunk = 0; chunk < len; chunk += 64) {
        const int m = min(64, len - chunk);
        int idx = 0;
        if (lane < m) idx = srcs_sorted[start + chunk + lane];

        int t = 0;
        #pragma unroll 4
        for (; t + 4 <= m; t += 4) {
            const int s = __shfl(idx, t + quarter);
            const uint4 y = *(const uint4*)(Zb + (size_t)s * 128 + cl);
            const float f0 = __uint_as_float((y.x & 0xffffu) << 16);
            const float f1 = __uint_as_float(y.x & 0xffff0000u);
            const float f2 = __uint_as_float((y.y & 0xffffu) << 16);
            const float f3 = __uint_as_float(y.y & 0xffff0000u);
            const float f4 = __uint_as_float((y.z & 0xffffu) << 16);
            const float f5 = __uint_as_float(y.z & 0xffff0000u);
            const float f6 = __uint_as_float((y.w & 0xffffu) << 16);
            const float f7 = __uint_as_float(y.w & 0xffff0000u);
            const float z0 = f0 + qd[0], z1 = f1 + qd[1];
            const float z2 = f2 + qd[2], z3 = f3 + qd[3];
            const float z4 = f4 + qd[4], z5 = f5 + qd[5];
            const float z6 = f6 + qd[6], z7 = f7 + qd[7];
            acc[0] += fmaxf(z0, 0.01f * z0);
            acc[1] += fmaxf(z1, 0.01f * z1);
            acc[2] += fmaxf(z2, 0.01f * z2);
            acc[3] += fmaxf(z3, 0.01f * z3);
            acc[4] += fmaxf(z4, 0.01f * z4);
            acc[5] += fmaxf(z5, 0.01f * z5);
            acc[6] += fmaxf(z6, 0.01f * z6);
            acc[7] += fmaxf(z7, 0.01f * z7);
        }
        if (t < m) {   // tail: up to 3 edges, predicated per-quarter
            const int e = t + quarter;       // <= 63 always
            const int s = __shfl(idx, e);
            if (e < m) {
                const uint4 y = *(const uint4*)(Zb + (size_t)s * 128 + cl);
                const float f0 = __uint_as_float((y.x & 0xffffu) << 16);
                const float f1 = __uint_as_float(y.x & 0xffff0000u);
                const float f2 = __uint_as_float((y.y & 0xffffu) << 16);
                const float f3 = __uint_as_float(y.y & 0xffff0000u);
                const float f4 = __uint_as_float((y.z & 0xffffu) << 16);
                const float f5 = __uint_as_float(y.z & 0xffff0000u);
                const float f6 = __uint_as_float((y.w & 0xffffu) << 16);
                const float f7 = __uint_as_float(y.w & 0xffff0000u);
                const float z0 = f0 + qd[0], z1 = f1 + qd[1];
                const float z2 = f2 + qd[2], z3 = f3 + qd[3];
                const float z4 = f4 + qd[4], z5 = f5 + qd[5];
                const float z6 = f6 + qd[6], z7 = f7 + qd[7];
                acc[0] += fmaxf(z0, 0.01f * z0);
                acc[1] += fmaxf(z1, 0.01f * z1);
                acc[2] += fmaxf(z2, 0.01f * z2);
                acc[3] += fmaxf(z3, 0.01f * z3);
                acc[4] += fmaxf(z4, 0.01f * z4);
                acc[5] += fmaxf(z5, 0.01f * z5);
                acc[6] += fmaxf(z6, 0.01f * z6);
                acc[7] += fmaxf(z7, 0.01f * z7);
            }
        }
    }

    #pragma unroll
    for (int j = 0; j < 8; ++j) {
        acc[j] += __shfl_xor(acc[j], 16);
        acc[j] += __shfl_xor(acc[j], 32);
    }
    if (quarter == 0) {
        *(float4*)(aggr + (size_t)d * 128 + cl) =
            make_float4(acc[0], acc[1], acc[2], acc[3]);
        *(float4*)(aggr + (size_t)d * 128 + cl + 4) =
            make_float4(acc[4], acc[5], acc[6], acc[7]);
    }
}

// ---------------- gemm_g (MFMA, LDS-staged weights): out = leaky(aggr@g_w1+b1)@g_w2+b2+x ----
__global__ __launch_bounds__(256) void gemm_g(
    const float* __restrict__ aggr,
    const unsigned short* __restrict__ G1t, const float* __restrict__ g_b1,
    const unsigned short* __restrict__ G2t, const float* __restrict__ g_b2,
    const float* __restrict__ x,
    float* __restrict__ out, int N)
{
    __shared__ unsigned short Ws[128][136];
    __shared__ unsigned short Ts[64][136];

    const int tid  = threadIdx.x;
    const int lane = tid & 63;
    const int wave = tid >> 6;
    const int quad = lane >> 4;
    const int l16  = lane & 15;
    const int row0 = blockIdx.x * 64 + wave * 16;

    stage_weight(G1t, Ws, tid);

    bf16x8 a[4];
    {
        const int row = row0 + l16;
        if (row < N) {
            const float* ap = aggr + (size_t)row * 128 + quad * 8;
            #pragma unroll
            for (int kc = 0; kc < 4; ++kc) a[kc] = cvt8(ap + kc * 32);
        } else {
            #pragma unroll
            for (int kc = 0; kc < 4; ++kc) a[kc] = zero_ab();
        }
    }
    __syncthreads();

    f32x4 acc[8];
    #pragma unroll
    for (int nt = 0; nt < 8; ++nt) acc[nt] = (f32x4){0.f, 0.f, 0.f, 0.f};
    #pragma unroll
    for (int nt = 0; nt < 8; ++nt) {
        const unsigned short* wp = &Ws[nt * 16 + l16][quad * 8];
        #pragma unroll
        for (int kc = 0; kc < 4; ++kc) {
            const bf16x8 b = *(const bf16x8*)(wp + kc * 32);
            acc[nt] = __builtin_amdgcn_mfma_f32_16x16x32_bf16(a[kc], b, acc[nt], 0, 0, 0);
        }
    }

    #pragma unroll
    for (int nt = 0; nt < 8; ++nt) {
        const int col = nt * 16 + l16;
        const float b1 = g_b1[col];
        #pragma unroll
        for (int reg = 0; reg < 4; ++reg) {
            float t = acc[nt][reg] + b1;
            t = LEAKY(t);
            Ts[wave * 16 + quad * 4 + reg][col] = f2bf(t);
        }
    }
    __syncthreads();
    stage_weight(G2t, Ws, tid);
    __syncthreads();

    bf16x8 a2[4];
    {
        const unsigned short* tp = &Ts[wave * 16 + l16][quad * 8];
        #pragma unroll
        for (int kc = 0; kc < 4; ++kc) a2[kc] = *(const bf16x8*)(tp + kc * 32);
    }

    f32x4 acc2[8];
    #pragma unroll
    for (int nt = 0; nt < 8; ++nt) acc2[nt] = (f32x4){0.f, 0.f, 0.f, 0.f};
    #pragma unroll
    for (int nt = 0; nt < 8; ++nt) {
        const unsigned short* wp = &Ws[nt * 16 + l16][quad * 8];
        #pragma unroll
        for (int kc = 0; kc < 4; ++kc) {
            const bf16x8 b = *(const bf16x8*)(wp + kc * 32);
            acc2[nt] = __builtin_amdgcn_mfma_f32_16x16x32_bf16(a2[kc], b, acc2[nt], 0, 0, 0);
        }
    }

    #pragma unroll
    for (int nt = 0; nt < 8; ++nt) {
        const int col = nt * 16 + l16;
        const float b2 = g_b2[col];
        #pragma unroll
        for (int reg = 0; reg < 4; ++reg) {
            const int grow = row0 + quad * 4 + reg;
            if (grow < N)
                out[(size_t)grow * 128 + col] =
                    acc2[nt][reg] + b2 + x[(size_t)grow * 128 + col];
        }
    }
}

// ---------------- launch ----------------
extern "C" void kernel_launch(void* const* d_in, const int* in_sizes, int n_in,
                              void* d_out, int out_size, void* d_ws, size_t ws_size,
                              hipStream_t stream) {
    const float* x    = (const float*)d_in[0];
    const float* pos  = (const float*)d_in[1];
    const int*   ei   = (const int*)d_in[2];
    const float* h_w1 = (const float*)d_in[3];
    const float* h_b1 = (const float*)d_in[4];
    const float* h_w2 = (const float*)d_in[5];
    const float* h_b2 = (const float*)d_in[6];
    const float* f_w  = (const float*)d_in[7];   // [131,128]
    const float* f_b  = (const float*)d_in[8];
    const float* g_w1 = (const float*)d_in[9];
    const float* g_b1 = (const float*)d_in[10];
    const float* g_w2 = (const float*)d_in[11];
    const float* g_b2 = (const float*)d_in[12];
    float* out = (float*)d_out;

    const int N = in_sizes[0] / 128;
    const int E = in_sizes[2] / 2;

    // ws (~14.8 MB): deltap[N*3]f32 | Zb[N*128]u16 | counts[N] | offs[N] | bsums[1024] |
    //                srcs[E]u16 | Wht/Wft/G1t/G2t [128*128]u16 each
    float* deltap         = (float*)d_ws;
    unsigned short* Zb    = (unsigned short*)(deltap + (size_t)N * 3);
    int* counts           = (int*)(Zb + (size_t)N * 128);
    int* offs             = counts + N;
    int* bsums            = offs + N;
    unsigned short* srcs  = (unsigned short*)(bsums + 1024);
    unsigned short* Wht   = srcs + (size_t)E;
    unsigned short* Wft   = Wht + 128 * 128;
    unsigned short* G1t   = Wft + 128 * 128;
    unsigned short* G2t   = G1t + 128 * 128;
    float* aggr           = out;

    const int tile_blocks = (N + 63) / 64;
    const int hist_blocks = (E + 255) / 256;
    const int B = (N + 1023) / 1024;

    hipMemsetAsync(counts, 0, (size_t)N * sizeof(int), stream);

    prep_weights<<<128, 128, 0, stream>>>(h_w1, f_w, g_w1, g_w2, Wht, Wft, G1t, G2t);

    hist_kernel<<<hist_blocks, 256, 0, stream>>>(ei, counts, E);

    node_pre<<<tile_blocks, 256, 0, stream>>>(x, pos, Wht, h_b1, h_w2, h_b2, Wft, f_b,
                                              f_w, deltap, Zb, N);

    scan_local<<<B, 256, 0, stream>>>(counts, offs, bsums, N);
    scan_top<<<1, 256, 0, stream>>>(bsums, B);
    scan_fixup<<<B, 256, 0, stream>>>(offs, bsums, N);

    scatter_kernel<<<hist_blocks, 256, 0, stream>>>(ei, offs, srcs, E);

    aggregate_kernel<<<(N + 3) / 4, 256, 0, stream>>>(
        srcs, offs, counts, deltap, Zb, f_w, aggr, N);

    gemm_g<<<tile_blocks, 256, 0, stream>>>(aggr, G1t, g_b1, G2t, g_b2, x, out, N);
}